// Round 1
// baseline (801.474 us; speedup 1.0000x reference)
//
#include <hip/hip_runtime.h>
#include <stdint.h>

typedef __attribute__((ext_vector_type(8))) short short8;
typedef __attribute__((ext_vector_type(4))) short short4_;
typedef __attribute__((ext_vector_type(4))) float floatx4;

#define MFMA16(a,b,c) __builtin_amdgcn_mfma_f32_16x16x32_bf16((a),(b),(c),0,0,0)

__device__ __forceinline__ short f2b(float f) {
  union { float f; uint32_t u; } v; v.f = f;
  uint32_t r = v.u + 0x7fffu + ((v.u >> 16) & 1u);
  return (short)(r >> 16);
}

// ---------------- pack / convert kernels ----------------

// kvin_b[b][r][c] = bf16(concat(cmem, mem, x))  (4 x 2304 x 1024)
__global__ __launch_bounds__(256) void pack_kvin(const float* __restrict__ x,
    const float* __restrict__ mem, const float* __restrict__ cmem,
    short* __restrict__ out) {
  long idx = (long)blockIdx.x * 256 + threadIdx.x;
  long base = idx * 4;
  if (base >= 9437184L) return;
  int b = (int)(base / 2359296L);
  int rem = (int)(base - (long)b * 2359296L);
  int r = rem >> 10, c = rem & 1023;
  const float* src;
  if (r < 256)       src = cmem + ((long)b * 256  + r)          * 1024 + c;
  else if (r < 1280) src = mem  + ((long)b * 1024 + (r - 256))  * 1024 + c;
  else               src = x    + ((long)b * 1024 + (r - 1280)) * 1024 + c;
  float4 v = *(const float4*)src;
  short4_ o; o.x = f2b(v.x); o.y = f2b(v.y); o.z = f2b(v.z); o.w = f2b(v.w);
  *(short4_*)(out + base) = o;
}

__global__ __launch_bounds__(256) void pack_cvt(const float* __restrict__ in,
    short* __restrict__ out, long n4) {
  long idx = (long)blockIdx.x * 256 + threadIdx.x;
  if (idx >= n4) return;
  long base = idx * 4;
  float4 v = *(const float4*)(in + base);
  short4_ o; o.x = f2b(v.x); o.y = f2b(v.y); o.z = f2b(v.z); o.w = f2b(v.w);
  *(short4_*)(out + base) = o;
}

// conv weight pack: out[co][t*1024+ci] = bf16(conv_w[co][ci][t])
__global__ __launch_bounds__(256) void pack_convw(const float* __restrict__ cw,
    short* __restrict__ out) {
  long idx = (long)blockIdx.x * 256 + threadIdx.x;
  long base = idx * 4;
  if (base >= 4194304L) return;
  int co = (int)(base >> 12);
  int r  = (int)(base & 4095);
  int tt = r >> 10, ci = r & 1023;
  const float* s = cw + (long)co * 4096 + tt;
  short4_ o;
  o.x = f2b(s[(ci + 0) * 4]); o.y = f2b(s[(ci + 1) * 4]);
  o.z = f2b(s[(ci + 2) * 4]); o.w = f2b(s[(ci + 3) * 4]);
  *(short4_*)(out + base) = o;
}

// W (R x C fp32) -> Wt (C x R bf16)
__global__ __launch_bounds__(256) void transpose_w(const float* __restrict__ in,
    short* __restrict__ out, int R, int C) {
  __shared__ float tile[32][33];
  int bx = blockIdx.x << 5, by = blockIdx.y << 5;
  int tx = threadIdx.x, ty = threadIdx.y;
#pragma unroll
  for (int yy = 0; yy < 4; ++yy)
    tile[ty + 8 * yy][tx] = in[(long)(by + ty + 8 * yy) * C + bx + tx];
  __syncthreads();
#pragma unroll
  for (int yy = 0; yy < 4; ++yy)
    out[(long)(bx + ty + 8 * yy) * R + by + tx] = f2b(tile[tx][ty + 8 * yy]);
}

// per-(b,h): v_r[j][d] (2304x64 bf16) -> vt[d][j] (64x2304 bf16)
__global__ __launch_bounds__(256) void transpose_v(const short* __restrict__ in,
    short* __restrict__ out) {
  __shared__ short tile[32][33];
  int bh = blockIdx.z;
  int j0 = blockIdx.x << 5, d0 = blockIdx.y << 5;
  int tx = threadIdx.x, ty = threadIdx.y;
  const short* ip = in + (long)bh * 147456;
  short* op = out + (long)bh * 147456;
#pragma unroll
  for (int yy = 0; yy < 4; ++yy)
    tile[ty + 8 * yy][tx] = ip[(long)(j0 + ty + 8 * yy) * 64 + d0 + tx];
  __syncthreads();
#pragma unroll
  for (int yy = 0; yy < 4; ++yy)
    op[(long)(d0 + ty + 8 * yy) * 2304 + j0 + tx] = tile[tx][ty + 8 * yy];
}

// ---------------- GEMM: C = A(MxK) @ Bt(NxK)^T, bf16 MFMA, 128x128 tile ----
// MODE 0: Cf[row][col] = acc + bias[col]              (fp32 out)
// MODE 1: q layout   Ck[((b*16+h)*1024+i)*64+d]       (bf16)
// MODE 2: k/v split  Ck/Cv[((b*16+h)*2304+j)*64+d]    (bf16)
template<int MODE>
__global__ __launch_bounds__(256) void gemm_bt(
    const short* __restrict__ A, const short* __restrict__ Bt,
    float* __restrict__ Cf, short* __restrict__ Ck, short* __restrict__ Cv,
    const float* __restrict__ bias,
    int M, int N, int K, int a_rpb, long a_bstride, int a_row0, int a_lda) {
  __shared__ __align__(16) short As[128][40];
  __shared__ __align__(16) short Bs[128][40];
  int t = threadIdx.x;
  int w = t >> 6, lane = t & 63;
  int wr = (w >> 1) << 6, wc = (w & 1) << 6;
  int lrow = lane & 15, lk8 = (lane >> 4) << 3, lq4 = (lane >> 4) << 2;
  int rowblk = blockIdx.y << 7, colblk = blockIdx.x << 7;

  floatx4 acc[4][4];
#pragma unroll
  for (int i = 0; i < 4; ++i)
#pragma unroll
    for (int j = 0; j < 4; ++j) acc[i][j] = (floatx4){0.f, 0.f, 0.f, 0.f};

  int r0 = t >> 2, kc0 = (t & 3) << 3;
  int r1 = r0 + 64;
  int gr0 = rowblk + r0, gr1 = rowblk + r1;
  int b0 = gr0 / a_rpb, rr0 = gr0 - b0 * a_rpb;
  int b1 = gr1 / a_rpb, rr1 = gr1 - b1 * a_rpb;
  const short* a0p = A + b0 * a_bstride + (long)(a_row0 + rr0) * a_lda + kc0;
  const short* a1p = A + b1 * a_bstride + (long)(a_row0 + rr1) * a_lda + kc0;
  const short* b0p = Bt + (long)(colblk + r0) * K + kc0;
  const short* b1p = Bt + (long)(colblk + r1) * K + kc0;

  for (int k0 = 0; k0 < K; k0 += 32) {
    __syncthreads();
    *(uint4*)(&As[r0][kc0]) = *(const uint4*)(a0p + k0);
    *(uint4*)(&As[r1][kc0]) = *(const uint4*)(a1p + k0);
    *(uint4*)(&Bs[r0][kc0]) = *(const uint4*)(b0p + k0);
    *(uint4*)(&Bs[r1][kc0]) = *(const uint4*)(b1p + k0);
    __syncthreads();
    short8 af[4], bf[4];
#pragma unroll
    for (int mm = 0; mm < 4; ++mm) af[mm] = *(const short8*)(&As[wr + (mm << 4) + lrow][lk8]);
#pragma unroll
    for (int nn = 0; nn < 4; ++nn) bf[nn] = *(const short8*)(&Bs[wc + (nn << 4) + lrow][lk8]);
#pragma unroll
    for (int mm = 0; mm < 4; ++mm)
#pragma unroll
      for (int nn = 0; nn < 4; ++nn)
        acc[mm][nn] = MFMA16(af[mm], bf[nn], acc[mm][nn]);
  }

#pragma unroll
  for (int mm = 0; mm < 4; ++mm) {
#pragma unroll
    for (int nn = 0; nn < 4; ++nn) {
#pragma unroll
      for (int q = 0; q < 4; ++q) {
        int grow = rowblk + wr + (mm << 4) + lq4 + q;
        int gcol = colblk + wc + (nn << 4) + (lane & 15);
        float v = acc[mm][nn][q];
        if (MODE == 0) {
          Cf[(long)grow * N + gcol] = v + bias[gcol];
        } else if (MODE == 1) {
          int b = grow >> 10, i = grow & 1023, hh = gcol >> 6, d = gcol & 63;
          Ck[(((long)(b * 16 + hh)) * 1024 + i) * 64 + d] = f2b(v);
        } else {
          int b = grow / 2304, j = grow - b * 2304;
          if (gcol < 1024) {
            int hh = gcol >> 6, d = gcol & 63;
            Ck[(((long)(b * 16 + hh)) * 2304 + j) * 64 + d] = f2b(v);
          } else {
            int c2 = gcol - 1024, hh = c2 >> 6, d = c2 & 63;
            Cv[(((long)(b * 16 + hh)) * 2304 + j) * 64 + d] = f2b(v);
          }
        }
      }
    }
  }
}

// 64x64-tile variant (fp32 out + bias) for the small conv GEMM (grid occupancy)
__global__ __launch_bounds__(256) void gemm64_bias(const short* __restrict__ A,
    const short* __restrict__ Bt, float* __restrict__ Cf,
    const float* __restrict__ bias,
    int N, int K, int a_rpb, long a_bstride, int a_lda) {
  __shared__ __align__(16) short As[64][40];
  __shared__ __align__(16) short Bs[64][40];
  int t = threadIdx.x;
  int w = t >> 6, lane = t & 63;
  int wr = (w >> 1) << 5, wc = (w & 1) << 5;
  int lrow = lane & 15, lk8 = (lane >> 4) << 3, lq4 = (lane >> 4) << 2;
  int rowblk = blockIdx.y << 6, colblk = blockIdx.x << 6;
  floatx4 acc[2][2];
#pragma unroll
  for (int i = 0; i < 2; ++i)
#pragma unroll
    for (int j = 0; j < 2; ++j) acc[i][j] = (floatx4){0.f, 0.f, 0.f, 0.f};

  int r0 = t >> 2, kc0 = (t & 3) << 3;
  int gr0 = rowblk + r0;
  int b0 = gr0 / a_rpb, rr0 = gr0 - b0 * a_rpb;
  const short* a0p = A + b0 * a_bstride + (long)rr0 * a_lda + kc0;
  const short* b0p = Bt + (long)(colblk + r0) * K + kc0;

  for (int k0 = 0; k0 < K; k0 += 32) {
    __syncthreads();
    *(uint4*)(&As[r0][kc0]) = *(const uint4*)(a0p + k0);
    *(uint4*)(&Bs[r0][kc0]) = *(const uint4*)(b0p + k0);
    __syncthreads();
    short8 af[2], bf[2];
#pragma unroll
    for (int mm = 0; mm < 2; ++mm) af[mm] = *(const short8*)(&As[wr + (mm << 4) + lrow][lk8]);
#pragma unroll
    for (int nn = 0; nn < 2; ++nn) bf[nn] = *(const short8*)(&Bs[wc + (nn << 4) + lrow][lk8]);
#pragma unroll
    for (int mm = 0; mm < 2; ++mm)
#pragma unroll
      for (int nn = 0; nn < 2; ++nn)
        acc[mm][nn] = MFMA16(af[mm], bf[nn], acc[mm][nn]);
  }
#pragma unroll
  for (int mm = 0; mm < 2; ++mm)
#pragma unroll
    for (int nn = 0; nn < 2; ++nn)
#pragma unroll
      for (int q = 0; q < 4; ++q) {
        int grow = rowblk + wr + (mm << 4) + lq4 + q;
        int gcol = colblk + wc + (nn << 4) + (lane & 15);
        Cf[(long)grow * N + gcol] = acc[mm][nn][q] + bias[gcol];
      }
}

// ---------------- attention (flash-style, banded rel-pos) ----------------
// grid 4096 = (b*16+h)*64 + i_tile ; 1 wave ; 16 q-rows x 32-kv tiles
__global__ __launch_bounds__(64) void attn_kernel(
    const short* __restrict__ q_r, const short* __restrict__ k_r,
    const short* __restrict__ vt, const short* __restrict__ pe_b,
    short* __restrict__ attn_out) {
  __shared__ float T_lds[16][49];
  __shared__ __align__(16) short P_lds[16][40];
  int blk = blockIdx.x;
  int it = blk & 63, bh = blk >> 6;
  int b = bh >> 4, h = bh & 15;
  int i0 = it << 4;
  int lane = threadIdx.x;
  int lrow = lane & 15, g = lane >> 4;
  int lk8 = g << 3, lq4 = g << 2;

  const short* qbase = q_r + ((long)(bh * 1024 + i0 + lrow) << 6);
  short8 qa0 = *(const short8*)(qbase + lk8);
  short8 qa1 = *(const short8*)(qbase + 32 + lk8);

  floatx4 o0 = {0.f,0.f,0.f,0.f}, o1 = o0, o2 = o0, o3 = o0;
  float m[4], l[4];
#pragma unroll
  for (int q = 0; q < 4; ++q) { m[q] = -1e30f; l[q] = 0.f; }

  const short* kb = k_r  + (long)bh * 2304 * 64;
  const short* vb = vt   + (long)bh * 64 * 2304;
  const short* pb = pe_b + (long)h * 2304 * 64;

  int ntiles = (i0 + 1296 + 31) >> 5;
  for (int t = 0; t < ntiles; ++t) {
    int j0 = t << 5;
    // S = Q K^T (two 16-col halves, K=64 via 2 mfma)
    floatx4 s0 = {0.f,0.f,0.f,0.f}, s1 = {0.f,0.f,0.f,0.f};
    {
      const short* kr0 = kb + (long)(j0 + lrow) * 64;
      s0 = MFMA16(qa0, *(const short8*)(kr0 + lk8), s0);
      s0 = MFMA16(qa1, *(const short8*)(kr0 + 32 + lk8), s0);
      const short* kr1 = kb + (long)(j0 + 16 + lrow) * 64;
      s1 = MFMA16(qa0, *(const short8*)(kr1 + lk8), s1);
      s1 = MFMA16(qa1, *(const short8*)(kr1 + 32 + lk8), s1);
    }
    // PE band: T[i][rloc] = q[i] . pe[rbase+rloc], rloc in [0,48)
    int rbase = j0 - i0 + 1008;
#pragma unroll
    for (int pt = 0; pt < 3; ++pt) {
      int r = rbase + (pt << 4) + lrow;
      short8 p0 = {0,0,0,0,0,0,0,0}, p1 = {0,0,0,0,0,0,0,0};
      if (r < 2304) {
        const short* pr = pb + (long)r * 64;
        p0 = *(const short8*)(pr + lk8);
        p1 = *(const short8*)(pr + 32 + lk8);
      }
      floatx4 ta = {0.f,0.f,0.f,0.f};
      ta = MFMA16(qa0, p0, ta);
      ta = MFMA16(qa1, p1, ta);
#pragma unroll
      for (int q = 0; q < 4; ++q) T_lds[lq4 + q][(pt << 4) + lrow] = ta[q];
    }
    __syncthreads();
    // combine + diagonal shift select + mask
    float sv0[4], sv1[4];
#pragma unroll
    for (int q = 0; q < 4; ++q) {
      int row = lq4 + q;
      int i = i0 + row;
      float a0 = (s0[q] + T_lds[row][lrow - row + 15]) * 0.125f;
      if (j0 + lrow > i + 1280) a0 = -1e30f;
      sv0[q] = a0;
      float a1 = (s1[q] + T_lds[row][16 + lrow - row + 15]) * 0.125f;
      if (j0 + 16 + lrow > i + 1280) a1 = -1e30f;
      sv1[q] = a1;
    }
    // online softmax (rows live in 16-lane groups)
#pragma unroll
    for (int q = 0; q < 4; ++q) {
      float mx = fmaxf(sv0[q], sv1[q]);
      mx = fmaxf(mx, __shfl_xor(mx, 1));
      mx = fmaxf(mx, __shfl_xor(mx, 2));
      mx = fmaxf(mx, __shfl_xor(mx, 4));
      mx = fmaxf(mx, __shfl_xor(mx, 8));
      float newm = fmaxf(m[q], mx);
      float alpha = __expf(m[q] - newm);
      m[q] = newm;
      float p0 = __expf(sv0[q] - newm);
      float p1 = __expf(sv1[q] - newm);
      float rs = p0 + p1;
      rs += __shfl_xor(rs, 1); rs += __shfl_xor(rs, 2);
      rs += __shfl_xor(rs, 4); rs += __shfl_xor(rs, 8);
      l[q] = l[q] * alpha + rs;
      o0[q] *= alpha; o1[q] *= alpha; o2[q] *= alpha; o3[q] *= alpha;
      P_lds[lq4 + q][lrow] = f2b(p0);
      P_lds[lq4 + q][16 + lrow] = f2b(p1);
    }
    __syncthreads();
    // PV: A = P (16x32), B = V^T rows (d-major) -> K=32 contraction
    short8 pa = *(const short8*)(&P_lds[lrow][lk8]);
    o0 = MFMA16(pa, *(const short8*)(vb + (long)(lrow) * 2304 + j0 + lk8), o0);
    o1 = MFMA16(pa, *(const short8*)(vb + (long)(16 + lrow) * 2304 + j0 + lk8), o1);
    o2 = MFMA16(pa, *(const short8*)(vb + (long)(32 + lrow) * 2304 + j0 + lk8), o2);
    o3 = MFMA16(pa, *(const short8*)(vb + (long)(48 + lrow) * 2304 + j0 + lk8), o3);
  }
  // epilogue: normalize, write attn_out[(b*1024+i)*1024 + h*64 + d] bf16
#pragma unroll
  for (int q = 0; q < 4; ++q) {
    float inv = 1.0f / l[q];
    long addr = ((long)(b * 1024 + i0 + lq4 + q)) * 1024 + h * 64 + lrow;
    attn_out[addr +  0] = f2b(o0[q] * inv);
    attn_out[addr + 16] = f2b(o1[q] * inv);
    attn_out[addr + 32] = f2b(o2[q] * inv);
    attn_out[addr + 48] = f2b(o3[q] * inv);
  }
}

// ---------------- residual + layernorm ----------------
__global__ __launch_bounds__(256) void ln_kernel(const float* __restrict__ x,
    const float* __restrict__ lp, const float* __restrict__ g,
    const float* __restrict__ bb, float* __restrict__ out) {
  int row = blockIdx.x, t = threadIdx.x;
  long base = (long)row * 1024 + t * 4;
  float4 a = *(const float4*)(x + base);
  float4 bo = *(const float4*)(lp + base);
  float v0 = a.x + bo.x, v1 = a.y + bo.y, v2 = a.z + bo.z, v3 = a.w + bo.w;
  float s1 = v0 + v1 + v2 + v3;
  float s2 = v0 * v0 + v1 * v1 + v2 * v2 + v3 * v3;
#pragma unroll
  for (int off = 1; off < 64; off <<= 1) {
    s1 += __shfl_xor(s1, off);
    s2 += __shfl_xor(s2, off);
  }
  __shared__ float r1[4], r2[4];
  int w = t >> 6;
  if ((t & 63) == 0) { r1[w] = s1; r2[w] = s2; }
  __syncthreads();
  float S1 = r1[0] + r1[1] + r1[2] + r1[3];
  float S2 = r2[0] + r2[1] + r2[2] + r2[3];
  float mu = S1 * (1.f / 1024.f);
  float var = S2 * (1.f / 1024.f) - mu * mu;
  float rs = rsqrtf(var + 1e-5f);
  float4 gv = *(const float4*)(g + t * 4);
  float4 bv = *(const float4*)(bb + t * 4);
  float4 o;
  o.x = (v0 - mu) * rs * gv.x + bv.x;
  o.y = (v1 - mu) * rs * gv.y + bv.y;
  o.z = (v2 - mu) * rs * gv.z + bv.z;
  o.w = (v3 - mu) * rs * gv.w + bv.w;
  *(float4*)(out + base) = o;
}

// new_mem = x (exact fp32 copy), aux_loss = 0
__global__ __launch_bounds__(256) void copy_x(const float* __restrict__ x,
    float* __restrict__ outmem, float* __restrict__ aux) {
  long i = (long)blockIdx.x * 256 + threadIdx.x;
  ((float4*)outmem)[i] = ((const float4*)x)[i];
  if (i == 0) aux[0] = 0.f;
}

// ---------------- launch ----------------
extern "C" void kernel_launch(void* const* d_in, const int* in_sizes, int n_in,
                              void* d_out, int out_size, void* d_ws, size_t ws_size,
                              hipStream_t stream) {
  const float* x    = (const float*)d_in[0];
  const float* mem  = (const float*)d_in[1];
  const float* cmem = (const float*)d_in[2];
  const float* pe   = (const float*)d_in[3];
  const float* Wq   = (const float*)d_in[5];
  const float* Wkv  = (const float*)d_in[6];
  const float* Wout = (const float*)d_in[7];
  const float* bout = (const float*)d_in[8];
  const float* lng  = (const float*)d_in[9];
  const float* lnb  = (const float*)d_in[10];
  const float* cw   = (const float*)d_in[11];
  const float* cb   = (const float*)d_in[12];

  char* ws = (char*)d_ws;
  short* kvin_b = (short*)(ws + 0);          // 4x2304x1024 bf16
  short* q_r    = (short*)(ws + 18874368);   // (b,h,1024,64)
  short* k_r    = (short*)(ws + 27262976);   // (b,h,2304,64)
  short* vtp    = (short*)(ws + 46137344);   // (b,h,64,2304)
  short* v_r    = (short*)(ws + 65011712);   // (b,h,2304,64) temp
  short* pe_b   = (short*)(ws + 83886080);   // (16,2304,64)
  short* wq_t   = (short*)(ws + 88604672);   // (1024,1024)
  short* wkv_t  = (short*)(ws + 90701824);   // (2048,1024)
  short* wout_t = (short*)(ws + 94896128);   // (1024,1024)
  short* cw_t   = (short*)(ws + 96993280);   // (1024,4096)
  short* attn_o = (short*)(ws + 105381888);  // (4096,1024) bf16
  float* lpre   = (float*)(ws + 113770496);  // (4096,1024) fp32

  float* out_logits = (float*)d_out;
  float* out_mem    = out_logits + 4194304;
  float* out_cmem   = out_logits + 8388608;
  float* out_aux    = out_logits + 9437184;

  // packs
  pack_kvin<<<9216, 256, 0, stream>>>(x, mem, cmem, kvin_b);
  pack_cvt<<<2304, 256, 0, stream>>>(pe, pe_b, 589824);
  transpose_w<<<dim3(32, 32), dim3(32, 8), 0, stream>>>(Wq, wq_t, 1024, 1024);
  transpose_w<<<dim3(64, 32), dim3(32, 8), 0, stream>>>(Wkv, wkv_t, 1024, 2048);
  transpose_w<<<dim3(32, 32), dim3(32, 8), 0, stream>>>(Wout, wout_t, 1024, 1024);
  pack_convw<<<4096, 256, 0, stream>>>(cw, cw_t);

  // q = x @ Wq            (A = x rows inside kvin_b)
  gemm_bt<1><<<dim3(8, 32), 256, 0, stream>>>(kvin_b, wq_t, nullptr, q_r, nullptr,
      nullptr, 4096, 1024, 1024, 1024, 2359296L, 1280, 1024);
  // kv = kvin @ Wkv -> k_r, v_r
  gemm_bt<2><<<dim3(16, 72), 256, 0, stream>>>(kvin_b, wkv_t, nullptr, k_r, v_r,
      nullptr, 9216, 2048, 1024, 2304, 2359296L, 0, 1024);
  transpose_v<<<dim3(72, 2, 64), dim3(32, 8), 0, stream>>>(v_r, vtp);

  attn_kernel<<<4096, 64, 0, stream>>>(q_r, k_r, vtp, pe_b, attn_o);

  // logits_pre = attn_o @ Wout + bout
  gemm_bt<0><<<dim3(8, 32), 256, 0, stream>>>(attn_o, wout_t, lpre, nullptr, nullptr,
      bout, 4096, 1024, 1024, 4096, 0L, 0, 1024);
  ln_kernel<<<4096, 256, 0, stream>>>(x, lpre, lng, lnb, out_logits);

  copy_x<<<4096, 256, 0, stream>>>(x, out_mem, out_aux);

  // new_cmem = conv(mem) as GEMM: A = bf16(mem) (reshaped, inside kvin_b), Bt = cw_t
  gemm64_bias<<<dim3(16, 16), 256, 0, stream>>>(kvin_b + 262144, cw_t, out_cmem,
      cb, 1024, 4096, 256, 2359296L, 4096);
}

// Round 2
// 641.173 us; speedup vs baseline: 1.2500x; 1.2500x over previous
//
#include <hip/hip_runtime.h>
#include <stdint.h>

typedef __attribute__((ext_vector_type(8))) short short8;
typedef __attribute__((ext_vector_type(4))) short short4_;
typedef __attribute__((ext_vector_type(4))) float floatx4;

#define MFMA16(a,b,c) __builtin_amdgcn_mfma_f32_16x16x32_bf16((a),(b),(c),0,0,0)

__device__ __forceinline__ short f2b(float f) {
  union { float f; uint32_t u; } v; v.f = f;
  uint32_t r = v.u + 0x7fffu + ((v.u >> 16) & 1u);
  return (short)(r >> 16);
}

__device__ __forceinline__ unsigned cvt_pk_bf16(float a, float b) {
  unsigned r;
  asm("v_cvt_pk_bf16_f32 %0, %1, %2" : "=v"(r) : "v"(a), "v"(b));
  return r;
}

// ---------------- pack / convert kernels ----------------

__global__ __launch_bounds__(256) void pack_kvin(const float* __restrict__ x,
    const float* __restrict__ mem, const float* __restrict__ cmem,
    short* __restrict__ out) {
  long idx = (long)blockIdx.x * 256 + threadIdx.x;
  long base = idx * 4;
  if (base >= 9437184L) return;
  int b = (int)(base / 2359296L);
  int rem = (int)(base - (long)b * 2359296L);
  int r = rem >> 10, c = rem & 1023;
  const float* src;
  if (r < 256)       src = cmem + ((long)b * 256  + r)          * 1024 + c;
  else if (r < 1280) src = mem  + ((long)b * 1024 + (r - 256))  * 1024 + c;
  else               src = x    + ((long)b * 1024 + (r - 1280)) * 1024 + c;
  float4 v = *(const float4*)src;
  short4_ o; o.x = f2b(v.x); o.y = f2b(v.y); o.z = f2b(v.z); o.w = f2b(v.w);
  *(short4_*)(out + base) = o;
}

__global__ __launch_bounds__(256) void pack_cvt(const float* __restrict__ in,
    short* __restrict__ out, long n4) {
  long idx = (long)blockIdx.x * 256 + threadIdx.x;
  if (idx >= n4) return;
  long base = idx * 4;
  float4 v = *(const float4*)(in + base);
  short4_ o; o.x = f2b(v.x); o.y = f2b(v.y); o.z = f2b(v.z); o.w = f2b(v.w);
  *(short4_*)(out + base) = o;
}

__global__ __launch_bounds__(256) void pack_convw(const float* __restrict__ cw,
    short* __restrict__ out) {
  long idx = (long)blockIdx.x * 256 + threadIdx.x;
  long base = idx * 4;
  if (base >= 4194304L) return;
  int co = (int)(base >> 12);
  int r  = (int)(base & 4095);
  int tt = r >> 10, ci = r & 1023;
  const float* s = cw + (long)co * 4096 + tt;
  short4_ o;
  o.x = f2b(s[(ci + 0) * 4]); o.y = f2b(s[(ci + 1) * 4]);
  o.z = f2b(s[(ci + 2) * 4]); o.w = f2b(s[(ci + 3) * 4]);
  *(short4_*)(out + base) = o;
}

__global__ __launch_bounds__(256) void transpose_w(const float* __restrict__ in,
    short* __restrict__ out, int R, int C) {
  __shared__ float tile[32][33];
  int bx = blockIdx.x << 5, by = blockIdx.y << 5;
  int tx = threadIdx.x, ty = threadIdx.y;
#pragma unroll
  for (int yy = 0; yy < 4; ++yy)
    tile[ty + 8 * yy][tx] = in[(long)(by + ty + 8 * yy) * C + bx + tx];
  __syncthreads();
#pragma unroll
  for (int yy = 0; yy < 4; ++yy)
    out[(long)(bx + ty + 8 * yy) * R + by + tx] = f2b(tile[tx][ty + 8 * yy]);
}

__global__ __launch_bounds__(256) void transpose_v(const short* __restrict__ in,
    short* __restrict__ out) {
  __shared__ short tile[32][33];
  int bh = blockIdx.z;
  int j0 = blockIdx.x << 5, d0 = blockIdx.y << 5;
  int tx = threadIdx.x, ty = threadIdx.y;
  const short* ip = in + (long)bh * 147456;
  short* op = out + (long)bh * 147456;
#pragma unroll
  for (int yy = 0; yy < 4; ++yy)
    tile[ty + 8 * yy][tx] = ip[(long)(j0 + ty + 8 * yy) * 64 + d0 + tx];
  __syncthreads();
#pragma unroll
  for (int yy = 0; yy < 4; ++yy)
    op[(long)(d0 + ty + 8 * yy) * 2304 + j0 + tx] = tile[tx][ty + 8 * yy];
}

// ---------------- GEMM: C = A(MxK) @ Bt(NxK)^T, bf16 MFMA, 128x128 tile ----
template<int MODE>
__global__ __launch_bounds__(256) void gemm_bt(
    const short* __restrict__ A, const short* __restrict__ Bt,
    float* __restrict__ Cf, short* __restrict__ Ck, short* __restrict__ Cv,
    const float* __restrict__ bias,
    int M, int N, int K, int a_rpb, long a_bstride, int a_row0, int a_lda) {
  __shared__ __align__(16) short As[128][40];
  __shared__ __align__(16) short Bs[128][40];
  int t = threadIdx.x;
  int w = t >> 6, lane = t & 63;
  int wr = (w >> 1) << 6, wc = (w & 1) << 6;
  int lrow = lane & 15, lk8 = (lane >> 4) << 3, lq4 = (lane >> 4) << 2;
  int rowblk = blockIdx.y << 7, colblk = blockIdx.x << 7;

  floatx4 acc[4][4];
#pragma unroll
  for (int i = 0; i < 4; ++i)
#pragma unroll
    for (int j = 0; j < 4; ++j) acc[i][j] = (floatx4){0.f, 0.f, 0.f, 0.f};

  int r0 = t >> 2, kc0 = (t & 3) << 3;
  int r1 = r0 + 64;
  int gr0 = rowblk + r0, gr1 = rowblk + r1;
  int b0 = gr0 / a_rpb, rr0 = gr0 - b0 * a_rpb;
  int b1 = gr1 / a_rpb, rr1 = gr1 - b1 * a_rpb;
  const short* a0p = A + b0 * a_bstride + (long)(a_row0 + rr0) * a_lda + kc0;
  const short* a1p = A + b1 * a_bstride + (long)(a_row0 + rr1) * a_lda + kc0;
  const short* b0p = Bt + (long)(colblk + r0) * K + kc0;
  const short* b1p = Bt + (long)(colblk + r1) * K + kc0;

  for (int k0 = 0; k0 < K; k0 += 32) {
    __syncthreads();
    *(uint4*)(&As[r0][kc0]) = *(const uint4*)(a0p + k0);
    *(uint4*)(&As[r1][kc0]) = *(const uint4*)(a1p + k0);
    *(uint4*)(&Bs[r0][kc0]) = *(const uint4*)(b0p + k0);
    *(uint4*)(&Bs[r1][kc0]) = *(const uint4*)(b1p + k0);
    __syncthreads();
    short8 af[4], bf[4];
#pragma unroll
    for (int mm = 0; mm < 4; ++mm) af[mm] = *(const short8*)(&As[wr + (mm << 4) + lrow][lk8]);
#pragma unroll
    for (int nn = 0; nn < 4; ++nn) bf[nn] = *(const short8*)(&Bs[wc + (nn << 4) + lrow][lk8]);
#pragma unroll
    for (int mm = 0; mm < 4; ++mm)
#pragma unroll
      for (int nn = 0; nn < 4; ++nn)
        acc[mm][nn] = MFMA16(af[mm], bf[nn], acc[mm][nn]);
  }

#pragma unroll
  for (int mm = 0; mm < 4; ++mm) {
#pragma unroll
    for (int nn = 0; nn < 4; ++nn) {
#pragma unroll
      for (int q = 0; q < 4; ++q) {
        int grow = rowblk + wr + (mm << 4) + lq4 + q;
        int gcol = colblk + wc + (nn << 4) + (lane & 15);
        float v = acc[mm][nn][q];
        if (MODE == 0) {
          Cf[(long)grow * N + gcol] = v + bias[gcol];
        } else if (MODE == 1) {
          int b = grow >> 10, i = grow & 1023, hh = gcol >> 6, d = gcol & 63;
          // fold softmax SCALE = DH^-0.5 = 0.125 into q
          Ck[(((long)(b * 16 + hh)) * 1024 + i) * 64 + d] = f2b(v * 0.125f);
        } else {
          int b = grow / 2304, j = grow - b * 2304;
          if (gcol < 1024) {
            int hh = gcol >> 6, d = gcol & 63;
            Ck[(((long)(b * 16 + hh)) * 2304 + j) * 64 + d] = f2b(v);
          } else {
            int c2 = gcol - 1024, hh = c2 >> 6, d = c2 & 63;
            Cv[(((long)(b * 16 + hh)) * 2304 + j) * 64 + d] = f2b(v);
          }
        }
      }
    }
  }
}

__global__ __launch_bounds__(256) void gemm64_bias(const short* __restrict__ A,
    const short* __restrict__ Bt, float* __restrict__ Cf,
    const float* __restrict__ bias,
    int N, int K, int a_rpb, long a_bstride, int a_lda) {
  __shared__ __align__(16) short As[64][40];
  __shared__ __align__(16) short Bs[64][40];
  int t = threadIdx.x;
  int w = t >> 6, lane = t & 63;
  int wr = (w >> 1) << 5, wc = (w & 1) << 5;
  int lrow = lane & 15, lk8 = (lane >> 4) << 3, lq4 = (lane >> 4) << 2;
  int rowblk = blockIdx.y << 6, colblk = blockIdx.x << 6;
  floatx4 acc[2][2];
#pragma unroll
  for (int i = 0; i < 2; ++i)
#pragma unroll
    for (int j = 0; j < 2; ++j) acc[i][j] = (floatx4){0.f, 0.f, 0.f, 0.f};

  int r0 = t >> 2, kc0 = (t & 3) << 3;
  int gr0 = rowblk + r0;
  int b0 = gr0 / a_rpb, rr0 = gr0 - b0 * a_rpb;
  const short* a0p = A + b0 * a_bstride + (long)rr0 * a_lda + kc0;
  const short* b0p = Bt + (long)(colblk + r0) * K + kc0;

  for (int k0 = 0; k0 < K; k0 += 32) {
    __syncthreads();
    *(uint4*)(&As[r0][kc0]) = *(const uint4*)(a0p + k0);
    *(uint4*)(&Bs[r0][kc0]) = *(const uint4*)(b0p + k0);
    __syncthreads();
    short8 af[2], bf[2];
#pragma unroll
    for (int mm = 0; mm < 2; ++mm) af[mm] = *(const short8*)(&As[wr + (mm << 4) + lrow][lk8]);
#pragma unroll
    for (int nn = 0; nn < 2; ++nn) bf[nn] = *(const short8*)(&Bs[wc + (nn << 4) + lrow][lk8]);
#pragma unroll
    for (int mm = 0; mm < 2; ++mm)
#pragma unroll
      for (int nn = 0; nn < 2; ++nn)
        acc[mm][nn] = MFMA16(af[mm], bf[nn], acc[mm][nn]);
  }
#pragma unroll
  for (int mm = 0; mm < 2; ++mm)
#pragma unroll
    for (int nn = 0; nn < 2; ++nn)
#pragma unroll
      for (int q = 0; q < 4; ++q) {
        int grow = rowblk + wr + (mm << 4) + lq4 + q;
        int gcol = colblk + wc + (nn << 4) + (lane & 15);
        Cf[(long)grow * N + gcol] = acc[mm][nn][q] + bias[gcol];
      }
}

// ---------------- attention: swapped-operand flash, 32 rows/wave, KVBLK=64 --
// grid 2048 = bh*32 + iblk ; 1 wave/block ; row-state lane-local (i = lane&15)
__global__ __launch_bounds__(64, 2) void attn_kernel(
    const short* __restrict__ q_r, const short* __restrict__ k_r,
    const short* __restrict__ vt, const short* __restrict__ pe_b,
    short* __restrict__ attn_out) {
  // T stored skewed: value T[row][c] at [row][c + row] (stride 97)
  __shared__ float T_skew[2][16][97];
  __shared__ __align__(16) short P_lds[2][16][72];
  int blk = blockIdx.x;
  int ib = blk & 31, bh = blk >> 5;
  int b = bh >> 4, h = bh & 15;
  int i0 = ib << 5;
  int lane = threadIdx.x;
  int l = lane & 15, g = lane >> 4;
  int k8 = g << 3;

  const short* qb = q_r + ((long)(bh * 1024 + i0) << 6);
  short8 qf[2][2];
#pragma unroll
  for (int m = 0; m < 2; ++m) {
    qf[m][0] = *(const short8*)(qb + (((m << 4) + l) << 6) + k8);
    qf[m][1] = *(const short8*)(qb + (((m << 4) + l) << 6) + 32 + k8);
  }

  const short* kb = k_r + (long)bh * 147456;
  const short* vb = vt  + (long)bh * 147456;
  const short* pb = pe_b + (long)h * 147456;

  floatx4 o[2][4];
#pragma unroll
  for (int m = 0; m < 2; ++m)
#pragma unroll
    for (int dc = 0; dc < 4; ++dc) o[m][dc] = (floatx4){0.f, 0.f, 0.f, 0.f};
  float mreg[2] = {-1e30f, -1e30f};
  float lreg[2] = {0.f, 0.f};

  int ntiles = ((i0 + 1311) >> 6) + 1;
  for (int tt = 0; tt < ntiles; ++tt) {
    int j0 = tt << 6;
    // K fragments: A-frag rows = j (4 sub-tiles x 2 d-halves), shared by chunks
    short8 kf[4][2];
#pragma unroll
    for (int jt = 0; jt < 4; ++jt) {
      const short* kr = kb + ((long)(j0 + (jt << 4) + l) << 6);
      kf[jt][0] = *(const short8*)(kr + k8);
      kf[jt][1] = *(const short8*)(kr + 32 + k8);
    }
    // V^T fragments: A-frag rows = d (4 d-chunks x 2 j-halves), shared by chunks
    short8 vf[4][2];
#pragma unroll
    for (int dc = 0; dc < 4; ++dc) {
      const short* vr = vb + (long)((dc << 4) + l) * 2304 + j0;
      vf[dc][0] = *(const short8*)(vr + k8);
      vf[dc][1] = *(const short8*)(vr + 32 + k8);
    }
#pragma unroll
    for (int m = 0; m < 2; ++m) {
      int i0c = i0 + (m << 4);
      if (j0 > i0c + 1295) continue;   // chunk fully masked (uniform)
      // S^T = K @ Q : lane holds S[i = i0c+l][j = j0 + 16*jt + 4g + q]
      floatx4 s[4];
#pragma unroll
      for (int jt = 0; jt < 4; ++jt) {
        s[jt] = (floatx4){0.f, 0.f, 0.f, 0.f};
        s[jt] = MFMA16(kf[jt][0], qf[m][0], s[jt]);
        s[jt] = MFMA16(kf[jt][1], qf[m][1], s[jt]);
      }
      // PE band: T[i][c] = q[i] . pe[rb + c], c in [0,80)
      int rb = j0 - i0c + 1008;
#pragma unroll
      for (int pt = 0; pt < 5; ++pt) {
        int r = rb + (pt << 4) + l;
        r = r < 2303 ? r : 2303;       // OOB rows only feed masked entries
        const short* pr = pb + ((long)r << 6);
        floatx4 ta = {0.f, 0.f, 0.f, 0.f};
        ta = MFMA16(qf[m][0], *(const short8*)(pr + k8), ta);
        ta = MFMA16(qf[m][1], *(const short8*)(pr + 32 + k8), ta);
        int row0 = g << 2;
#pragma unroll
        for (int q = 0; q < 4; ++q)
          T_skew[m][row0 + q][(pt << 4) + l + row0 + q] = ta[q];
      }
      __syncthreads();
      // combine + diagonal select (read col = jl + 15, conflict-light) + mask
      int lim = i0c + l + 1280 - j0;
      float p[4][4];
      float mx = -1e30f;
#pragma unroll
      for (int jt = 0; jt < 4; ++jt)
#pragma unroll
        for (int q = 0; q < 4; ++q) {
          int jl = (jt << 4) + (g << 2) + q;
          float v = s[jt][q] + T_skew[m][l][jl + 15];
          v = (jl > lim) ? -1e30f : v;
          p[jt][q] = v;
          mx = fmaxf(mx, v);
        }
      mx = fmaxf(mx, __shfl_xor(mx, 16));
      mx = fmaxf(mx, __shfl_xor(mx, 32));
      // defer-max (T13): rescale only when max grows by > 8
      if (__any(mx - mreg[m] > 8.f)) {
        float nm = fmaxf(mreg[m], mx);
        float al = __expf(mreg[m] - nm);
#pragma unroll
        for (int dc = 0; dc < 4; ++dc) o[m][dc] *= al;
        lreg[m] *= al;
        mreg[m] = nm;
      }
      float rs = 0.f;
#pragma unroll
      for (int jt = 0; jt < 4; ++jt)
#pragma unroll
        for (int q = 0; q < 4; ++q) {
          p[jt][q] = __expf(p[jt][q] - mreg[m]);
          rs += p[jt][q];
        }
      rs += __shfl_xor(rs, 16);
      rs += __shfl_xor(rs, 32);
      lreg[m] += rs;
      // pack P (bf16) into LDS rows = i
#pragma unroll
      for (int jt = 0; jt < 4; ++jt) {
        unsigned u0 = cvt_pk_bf16(p[jt][0], p[jt][1]);
        unsigned u1 = cvt_pk_bf16(p[jt][2], p[jt][3]);
        int c0 = (jt << 4) + (g << 2);
        *(unsigned*)&P_lds[m][l][c0]     = u0;
        *(unsigned*)&P_lds[m][l][c0 + 2] = u1;
      }
      __syncthreads();
      short8 pa0 = *(const short8*)&P_lds[m][l][k8];
      short8 pa1 = *(const short8*)&P_lds[m][l][32 + k8];
      // O^T += V^T @ P : lane holds Out[i = i0c+l][d = 16*dc + 4g + q]
#pragma unroll
      for (int dc = 0; dc < 4; ++dc) {
        o[m][dc] = MFMA16(vf[dc][0], pa0, o[m][dc]);
        o[m][dc] = MFMA16(vf[dc][1], pa1, o[m][dc]);
      }
    }
  }
  // epilogue: normalize (lane-local l), pack, store dwordx2
#pragma unroll
  for (int m = 0; m < 2; ++m) {
    float invl = 1.f / lreg[m];
    long rowbase = ((long)(b * 1024 + i0 + (m << 4) + l) << 10) + (h << 6) + (g << 2);
#pragma unroll
    for (int dc = 0; dc < 4; ++dc) {
      uint2 u;
      u.x = cvt_pk_bf16(o[m][dc][0] * invl, o[m][dc][1] * invl);
      u.y = cvt_pk_bf16(o[m][dc][2] * invl, o[m][dc][3] * invl);
      *(uint2*)(attn_out + rowbase + (dc << 4)) = u;
    }
  }
}

// ---------------- residual + layernorm ----------------
__global__ __launch_bounds__(256) void ln_kernel(const float* __restrict__ x,
    const float* __restrict__ lp, const float* __restrict__ g,
    const float* __restrict__ bb, float* __restrict__ out) {
  int row = blockIdx.x, t = threadIdx.x;
  long base = (long)row * 1024 + t * 4;
  float4 a = *(const float4*)(x + base);
  float4 bo = *(const float4*)(lp + base);
  float v0 = a.x + bo.x, v1 = a.y + bo.y, v2 = a.z + bo.z, v3 = a.w + bo.w;
  float s1 = v0 + v1 + v2 + v3;
  float s2 = v0 * v0 + v1 * v1 + v2 * v2 + v3 * v3;
#pragma unroll
  for (int off = 1; off < 64; off <<= 1) {
    s1 += __shfl_xor(s1, off);
    s2 += __shfl_xor(s2, off);
  }
  __shared__ float r1[4], r2[4];
  int w = t >> 6;
  if ((t & 63) == 0) { r1[w] = s1; r2[w] = s2; }
  __syncthreads();
  float S1 = r1[0] + r1[1] + r1[2] + r1[3];
  float S2 = r2[0] + r2[1] + r2[2] + r2[3];
  float mu = S1 * (1.f / 1024.f);
  float var = S2 * (1.f / 1024.f) - mu * mu;
  float rs = rsqrtf(var + 1e-5f);
  float4 gv = *(const float4*)(g + t * 4);
  float4 bv = *(const float4*)(bb + t * 4);
  float4 o;
  o.x = (v0 - mu) * rs * gv.x + bv.x;
  o.y = (v1 - mu) * rs * gv.y + bv.y;
  o.z = (v2 - mu) * rs * gv.z + bv.z;
  o.w = (v3 - mu) * rs * gv.w + bv.w;
  *(float4*)(out + base) = o;
}

__global__ __launch_bounds__(256) void copy_x(const float* __restrict__ x,
    float* __restrict__ outmem, float* __restrict__ aux) {
  long i = (long)blockIdx.x * 256 + threadIdx.x;
  ((float4*)outmem)[i] = ((const float4*)x)[i];
  if (i == 0) aux[0] = 0.f;
}

// ---------------- launch ----------------
extern "C" void kernel_launch(void* const* d_in, const int* in_sizes, int n_in,
                              void* d_out, int out_size, void* d_ws, size_t ws_size,
                              hipStream_t stream) {
  const float* x    = (const float*)d_in[0];
  const float* mem  = (const float*)d_in[1];
  const float* cmem = (const float*)d_in[2];
  const float* pe   = (const float*)d_in[3];
  const float* Wq   = (const float*)d_in[5];
  const float* Wkv  = (const float*)d_in[6];
  const float* Wout = (const float*)d_in[7];
  const float* bout = (const float*)d_in[8];
  const float* lng  = (const float*)d_in[9];
  const float* lnb  = (const float*)d_in[10];
  const float* cw   = (const float*)d_in[11];
  const float* cb   = (const float*)d_in[12];

  char* ws = (char*)d_ws;
  short* kvin_b = (short*)(ws + 0);          // 4x2304x1024 bf16
  short* q_r    = (short*)(ws + 18874368);   // (b,h,1024,64)  pre-scaled by 0.125
  short* k_r    = (short*)(ws + 27262976);   // (b,h,2304,64)
  short* vtp    = (short*)(ws + 46137344);   // (b,h,64,2304)
  short* v_r    = (short*)(ws + 65011712);   // (b,h,2304,64) temp
  short* pe_b   = (short*)(ws + 83886080);   // (16,2304,64)
  short* wq_t   = (short*)(ws + 88604672);   // (1024,1024)
  short* wkv_t  = (short*)(ws + 90701824);   // (2048,1024)
  short* wout_t = (short*)(ws + 94896128);   // (1024,1024)
  short* cw_t   = (short*)(ws + 96993280);   // (1024,4096)
  short* attn_o = (short*)(ws + 105381888);  // (4096,1024) bf16
  float* lpre   = (float*)(ws + 113770496);  // (4096,1024) fp32

  float* out_logits = (float*)d_out;
  float* out_mem    = out_logits + 4194304;
  float* out_cmem   = out_logits + 8388608;
  float* out_aux    = out_logits + 9437184;

  pack_kvin<<<9216, 256, 0, stream>>>(x, mem, cmem, kvin_b);
  pack_cvt<<<2304, 256, 0, stream>>>(pe, pe_b, 589824);
  transpose_w<<<dim3(32, 32), dim3(32, 8), 0, stream>>>(Wq, wq_t, 1024, 1024);
  transpose_w<<<dim3(64, 32), dim3(32, 8), 0, stream>>>(Wkv, wkv_t, 1024, 2048);
  transpose_w<<<dim3(32, 32), dim3(32, 8), 0, stream>>>(Wout, wout_t, 1024, 1024);
  pack_convw<<<4096, 256, 0, stream>>>(cw, cw_t);

  gemm_bt<1><<<dim3(8, 32), 256, 0, stream>>>(kvin_b, wq_t, nullptr, q_r, nullptr,
      nullptr, 4096, 1024, 1024, 1024, 2359296L, 1280, 1024);
  gemm_bt<2><<<dim3(16, 72), 256, 0, stream>>>(kvin_b, wkv_t, nullptr, k_r, v_r,
      nullptr, 9216, 2048, 1024, 2304, 2359296L, 0, 1024);
  transpose_v<<<dim3(72, 2, 64), dim3(32, 8), 0, stream>>>(v_r, vtp);

  attn_kernel<<<2048, 64, 0, stream>>>(q_r, k_r, vtp, pe_b, attn_o);

  gemm_bt<0><<<dim3(8, 32), 256, 0, stream>>>(attn_o, wout_t, lpre, nullptr, nullptr,
      bout, 4096, 1024, 1024, 4096, 0L, 0, 1024);
  ln_kernel<<<4096, 256, 0, stream>>>(x, lpre, lng, lnb, out_logits);

  copy_x<<<4096, 256, 0, stream>>>(x, out_mem, out_aux);

  gemm64_bias<<<dim3(16, 16), 256, 0, stream>>>(kvin_b + 262144, cw_t, out_cmem,
      cb, 1024, 4096, 256, 2359296L, 4096);
}